// Round 14
// baseline (365.137 us; speedup 1.0000x reference)
//
#include <hip/hip_runtime.h>
#include <cmath>

// x [B=4096][T=512][D=4], H=32, gates 4H=128 (PyTorch order i,f,g,o).
constexpr int T   = 512;
constexpr int D   = 4;
constexpr int H   = 32;
constexpr int BT  = 16;    // batch cols per block — ALL real
constexpr int BLK = 512;   // 8 waves: (layer, unit-half, act-sub)

constexpr float LOG2E     = 1.44269504088896340736f;
constexpr float NEG2LOG2E = -2.88539008177792681472f;

typedef short bf8 __attribute__((ext_vector_type(8)));  // 8 bf16 (4 VGPRs)
typedef short s2v __attribute__((ext_vector_type(2)));  // 2 bf16 (4B)
typedef float f4  __attribute__((ext_vector_type(4)));  // MFMA C/D
typedef float f2  __attribute__((ext_vector_type(2)));

// fp32 -> bf16 round-to-nearest-even
static __device__ __forceinline__ short bf16_rtn(float v) {
    unsigned u = __float_as_uint(v);
    u += 0x7FFFu + ((u >> 16) & 1u);
    return (short)(u >> 16);
}

// R13 body (single-product bf16 MFMAs, exp2-folded weights, plain-bf16 h,
// 1 barrier/iter) + sub-duplication to reach 2 waves/SIMD: wave pair
// (sub=0/1) computes IDENTICAL 8 MFMAs for (layer, ug), then splits the
// state update (sub owns quad-rows 2sub, 2sub+1). R12's failure mode —
// duplicated 840-cy dependent MFMA chains — is absent here (4 independent
// 2-chains, 264 cy/SIMD duplicated). Act also uses folded rcp:
//   i*g      = (1-eg) / ((1+ei)(1+eg))        [one rcp]
//   o*tanh(c)= (1-ec) / ((1+eo)(1+ec))        [one rcp]
//   f*c      = c / (1+ef)                     [one rcp]
__global__ __launch_bounds__(BLK, 1) void lstm_bf16d(
    const float* __restrict__ x,
    const float* __restrict__ W_ih0, const float* __restrict__ W_hh0,
    const float* __restrict__ b_ih0, const float* __restrict__ b_hh0,
    const float* __restrict__ W_ih1, const float* __restrict__ W_hh1,
    const float* __restrict__ b_ih1, const float* __restrict__ b_hh1,
    const float* __restrict__ W_out, const float* __restrict__ b_out,
    float* __restrict__ out)
{
    // [buf][col][unit], row stride 56 shorts = 112 B
    __shared__ __align__(16) short h0b[2][16][56];
    __shared__ __align__(16) short h1b[2][16][56];
    __shared__ __align__(16) float h1f[16][36];     // final h1 fp32 for the head

    const int tid   = threadIdx.x;
    const int w     = tid >> 6;
    const int lane  = tid & 63;
    const int q     = lane >> 4;            // quad
    const int nl    = lane & 15;            // batch col (all real)
    const int layer = w >> 2;               // 0: L1, 1: L2
    const int ug    = ((w >> 1) & 1) << 4;  // unit group offset 0 / 16
    const int sub   = w & 1;                // act split: rows 2sub, 2sub+1
    const int b0    = blockIdx.x * BT;

    // zero both h buffers
    for (int idx = tid; idx < 2 * 16 * 56; idx += BLK) {
        (&h0b[0][0][0])[idx] = 0;
        (&h1b[0][0][0])[idx] = 0;
    }

    // ---- weights: tile g = gate type. A-frag row = 32g + ug + nl, k = 8q+j.
    // W1 dotted with h0 (L1: W_hh0, L2: W_ih1); W2 with the 2nd operand
    // (L1: W_ih0 vs x, K-padded; L2: W_hh1 vs h1). Rows pre-scaled for exp2.
    const float* W1 = layer ? W_ih1 : W_hh0;
    bf8 w1[4], w2[4];
    f4  bias[4];
    #pragma unroll
    for (int g = 0; g < 4; ++g) {
        const float sc = (g == 2) ? NEG2LOG2E : -LOG2E;
        const int row = 32 * g + ug + nl;
        #pragma unroll
        for (int j = 0; j < 8; ++j) {
            w1[g][j] = bf16_rtn(W1[row * H + 8 * q + j] * sc);
            float v2 = layer ? W_hh1[row * H + 8 * q + j]
                             : ((q == 0 && j < 4) ? W_ih0[row * D + j] : 0.0f);
            w2[g][j] = bf16_rtn(v2 * sc);
        }
        #pragma unroll
        for (int r = 0; r < 4; ++r) {
            const int gr = 32 * g + ug + 4 * q + r;
            bias[g][r] = sc * (layer ? (b_ih1[gr] + b_hh1[gr])
                                     : (b_ih0[gr] + b_hh0[gr]));
        }
    }

    const float4* xp = (const float4*)(x + (size_t)(b0 + nl) * (T * D));
    float4 xcur;
    if (layer == 0) xcur = xp[0];

    float c[2] = {0.0f, 0.0f};   // cell state of the 2 owned units (fp32)

    __syncthreads();

    #pragma unroll 1
    for (int i = 0; i <= T; ++i) {
        const int rb = i & 1, wb = rb ^ 1;

        bf8 b2;
        if (layer == 0) {   // x(i): k<4 = x (A cols k>=4 are zero)
            bf8 z = {0,0,0,0,0,0,0,0};
            b2 = z;
            b2[0] = bf16_rtn(xcur.x);
            b2[1] = bf16_rtn(xcur.y);
            b2[2] = bf16_rtn(xcur.z);
            b2[3] = bf16_rtn(xcur.w);
            xcur = xp[(i + 1 < T) ? (i + 1) : (T - 1)];   // prefetch
        } else {            // h1(i-2)
            b2 = *(const bf8*)&h1b[rb][nl][8 * q];
        }
        bf8 b1 = *(const bf8*)&h0b[rb][nl][8 * q];        // h0(i-1)

        // ---- 8 MFMAs (duplicated across the sub pair): 4 x 2-chain ----
        f4 acc[4];
        #pragma unroll
        for (int g = 0; g < 4; ++g) {
            f4 A = __builtin_amdgcn_mfma_f32_16x16x32_bf16(w2[g], b2, bias[g], 0, 0, 0);
            A    = __builtin_amdgcn_mfma_f32_16x16x32_bf16(w1[g], b1, A,       0, 0, 0);
            acc[g] = A;
        }

        // ---- state update: 2 units/lane (quad rows 2sub, 2sub+1) ----
        // acc holds -log2e*z (i,f,o) / -2log2e*z (g): native exp2 domain.
        const bool act = layer ? (i >= 1) : (i < T);
        if (act) {
            s2v hh;
            float hv[2];
            #pragma unroll
            for (int r = 0; r < 2; ++r) {
                const int rr = 2 * sub + r;
                float ei = __builtin_amdgcn_exp2f(acc[0][rr]);
                float ef = __builtin_amdgcn_exp2f(acc[1][rr]);
                float eg = __builtin_amdgcn_exp2f(acc[2][rr]);
                float eo = __builtin_amdgcn_exp2f(acc[3][rr]);
                // i*g = (1-eg)/((1+ei)(1+eg)) ; f*c = c/(1+ef)
                float rig = __builtin_amdgcn_rcpf((1.0f + ei) * (1.0f + eg));
                float rf  = __builtin_amdgcn_rcpf(1.0f + ef);
                c[r] = fmaf(c[r], rf, (1.0f - eg) * rig);
                // o*tanh(c) = (1-ec)/((1+eo)(1+ec))
                float ec = __builtin_amdgcn_exp2f(c[r] * NEG2LOG2E);
                float rot = __builtin_amdgcn_rcpf((1.0f + eo) * (1.0f + ec));
                hv[r] = (1.0f - ec) * rot;
                hh[r] = bf16_rtn(hv[r]);
            }
            const int uo = ug + 4 * q + 2 * sub;
            if (layer == 0) {
                *(s2v*)&h0b[wb][nl][uo] = hh;
            } else {
                *(s2v*)&h1b[wb][nl][uo] = hh;
                if (i == T) {   // h1(T-1), fp32, for the output head
                    f2 hw; hw.x = hv[0]; hw.y = hv[1];
                    *(f2*)&h1f[nl][uo] = hw;
                }
            }
        }
        __syncthreads();   // single barrier: buffer wb becomes rb of iter i+1
    }

    // ---- output head: out[b0+n] = b_out + W_out . h1(T-1) ----
    if (tid < BT) {
        float acc = b_out[0];
        #pragma unroll
        for (int u = 0; u < H; ++u) acc = fmaf(W_out[u], h1f[tid][u], acc);
        out[b0 + tid] = acc;
    }
}

extern "C" void kernel_launch(void* const* d_in, const int* in_sizes, int n_in,
                              void* d_out, int out_size, void* d_ws, size_t ws_size,
                              hipStream_t stream) {
    const float* x     = (const float*)d_in[0];
    const float* W_ih0 = (const float*)d_in[1];
    const float* W_hh0 = (const float*)d_in[2];
    const float* b_ih0 = (const float*)d_in[3];
    const float* b_hh0 = (const float*)d_in[4];
    const float* W_ih1 = (const float*)d_in[5];
    const float* W_hh1 = (const float*)d_in[6];
    const float* b_ih1 = (const float*)d_in[7];
    const float* b_hh1 = (const float*)d_in[8];
    const float* W_out = (const float*)d_in[9];
    const float* b_out = (const float*)d_in[10];
    float* out = (float*)d_out;

    const int B = out_size;          // 4096
    lstm_bf16d<<<B / BT, BLK, 0, stream>>>(x, W_ih0, W_hh0, b_ih0, b_hh0,
                                           W_ih1, W_hh1, b_ih1, b_hh1,
                                           W_out, b_out, out);
}

// Round 15
// 295.500 us; speedup vs baseline: 1.2357x; 1.2357x over previous
//
#include <hip/hip_runtime.h>
#include <cmath>

// x [B=4096][T=512][D=4], H=32, gates 4H=128 (PyTorch order i,f,g,o).
constexpr int T   = 512;
constexpr int D   = 4;
constexpr int H   = 32;
constexpr int BT  = 16;    // batch cols per block — ALL real
constexpr int BLK = 256;   // 4 waves: (layer, unit-half)

constexpr float LOG2E     = 1.44269504088896340736f;
constexpr float NEG2LOG2E = -2.88539008177792681472f;

// x LDS: per-col stride 2052 shorts = 1026 dwords ≡ 2 (mod 32) -> the 16
// per-iter b64 broadcast reads land on 16 distinct bank-pairs (no conflict)
constexpr int XSTRIDE = 2052;

typedef short bf8 __attribute__((ext_vector_type(8)));  // 8 bf16 (4 VGPRs)
typedef short s4v __attribute__((ext_vector_type(4)));  // 4 bf16 (8B)
typedef float f4  __attribute__((ext_vector_type(4)));  // MFMA C/D

// fp32 -> bf16 round-to-nearest-even
static __device__ __forceinline__ short bf16_rtn(float v) {
    unsigned u = __float_as_uint(v);
    u += 0x7FFFu + ((u >> 16) & 1u);
    return (short)(u >> 16);
}

// R13 topology (best: wave = (layer, unit-half) owns all 4 gate tiles;
// lane-local i,f,g,o in C/D regs; single-product bf16 MFMAs with
// exp2-folded weights; plain-bf16 h; 1 barrier/iter) with the loop body
// slimmed: x pre-staged in LDS as bf16 (per-iter x-path = one broadcast
// ds_read_b64, no global loads / cvt in the loop), single-rcp c-update
// (7 trans/unit), manual 2x unroll with literal buffer indices.
__global__ __launch_bounds__(BLK, 1) void lstm_bf16s(
    const float* __restrict__ x,
    const float* __restrict__ W_ih0, const float* __restrict__ W_hh0,
    const float* __restrict__ b_ih0, const float* __restrict__ b_hh0,
    const float* __restrict__ W_ih1, const float* __restrict__ W_hh1,
    const float* __restrict__ b_ih1, const float* __restrict__ b_hh1,
    const float* __restrict__ W_out, const float* __restrict__ b_out,
    float* __restrict__ out)
{
    __shared__ __align__(16) short xbf[16 * XSTRIDE];   // 64.1 KB staged x (bf16)
    __shared__ __align__(16) short h0b[2][16][56];      // h, [buf][col][unit]
    __shared__ __align__(16) short h1b[2][16][56];
    __shared__ __align__(16) float h1f[16][36];         // final h1 fp32 for the head

    const int tid   = threadIdx.x;
    const int w     = tid >> 6;
    const int lane  = tid & 63;
    const int q     = lane >> 4;       // quad
    const int nl    = lane & 15;       // batch col (all real)
    const int layer = w >> 1;          // 0: L1, 1: L2
    const int ug    = (w & 1) << 4;    // unit group offset 0 / 16
    const int b0    = blockIdx.x * BT;

    // ---- stage x[b0+col][t][:] -> bf16 LDS (coalesced: consecutive tid = t) ----
    for (int idx = tid; idx < 16 * T; idx += BLK) {
        const int col = idx >> 9;          // /512
        const int t   = idx & (T - 1);
        float4 xv = *(const float4*)(x + ((size_t)(b0 + col) * T + t) * D);
        s4v v;
        v[0] = bf16_rtn(xv.x); v[1] = bf16_rtn(xv.y);
        v[2] = bf16_rtn(xv.z); v[3] = bf16_rtn(xv.w);
        *(s4v*)&xbf[col * XSTRIDE + t * 4] = v;
    }
    // zero both h buffers
    for (int idx = tid; idx < 2 * 16 * 56; idx += BLK) {
        (&h0b[0][0][0])[idx] = 0;
        (&h1b[0][0][0])[idx] = 0;
    }

    // ---- weights: tile g = gate type. A-frag row = 32g + ug + nl, k = 8q+j.
    // W1 dotted with h0 (L1: W_hh0, L2: W_ih1); W2 with the 2nd operand
    // (L1: W_ih0 vs x, K-padded; L2: W_hh1 vs h1). Rows pre-scaled for exp2.
    const float* W1 = layer ? W_ih1 : W_hh0;
    bf8 w1[4], w2[4];
    f4  bias[4];
    #pragma unroll
    for (int g = 0; g < 4; ++g) {
        const float sc = (g == 2) ? NEG2LOG2E : -LOG2E;
        const int row = 32 * g + ug + nl;
        #pragma unroll
        for (int j = 0; j < 8; ++j) {
            w1[g][j] = bf16_rtn(W1[row * H + 8 * q + j] * sc);
            float v2 = layer ? W_hh1[row * H + 8 * q + j]
                             : ((q == 0 && j < 4) ? W_ih0[row * D + j] : 0.0f);
            w2[g][j] = bf16_rtn(v2 * sc);
        }
        #pragma unroll
        for (int r = 0; r < 4; ++r) {
            const int gr = 32 * g + ug + 4 * q + r;
            bias[g][r] = sc * (layer ? (b_ih1[gr] + b_hh1[gr])
                                     : (b_ih0[gr] + b_hh0[gr]));
        }
    }

    float c[4] = {0.0f, 0.0f, 0.0f, 0.0f};   // cell state, fp32, lane-local

    __syncthreads();

    // ---- one timestep; rb/wb are compile-time literals at each call site ----
    auto body = [&](const int i, const int rb, const int wb) {
        bf8 b2;
        if (layer == 0) {   // x(i): k<4 = x (A cols k>=4 are zero)
            const int t = (i < T) ? i : (T - 1);
            s4v xv = *(const s4v*)&xbf[nl * XSTRIDE + t * 4];   // broadcast b64
            bf8 z = {0,0,0,0,0,0,0,0};
            b2 = z;
            b2[0] = xv[0]; b2[1] = xv[1]; b2[2] = xv[2]; b2[3] = xv[3];
        } else {            // h1(i-2)
            b2 = *(const bf8*)&h1b[rb][nl][8 * q];
        }
        bf8 b1 = *(const bf8*)&h0b[rb][nl][8 * q];              // h0(i-1)

        // ---- 8 MFMAs: 4 gate tiles x 2-chain (C starts at scaled bias) ----
        f4 acc[4];
        #pragma unroll
        for (int g = 0; g < 4; ++g) {
            f4 A = __builtin_amdgcn_mfma_f32_16x16x32_bf16(w2[g], b2, bias[g], 0, 0, 0);
            A    = __builtin_amdgcn_mfma_f32_16x16x32_bf16(w1[g], b1, A,       0, 0, 0);
            acc[g] = A;
        }

        // ---- lane-local state update: units ug+4q+r, col nl ----
        // acc = -log2e*z (i,f,o) / -2log2e*z (g): native exp2 domain.
        const bool act = layer ? (i >= 1) : (i < T);
        if (act) {
            s4v hh;
            float hv[4];
            #pragma unroll
            for (int r = 0; r < 4; ++r) {
                float ei = __builtin_amdgcn_exp2f(acc[0][r]);
                float ef = __builtin_amdgcn_exp2f(acc[1][r]);
                float eg = __builtin_amdgcn_exp2f(acc[2][r]);
                float eo = __builtin_amdgcn_exp2f(acc[3][r]);
                // c' = c/(1+ef) + (1-eg)/((1+ei)(1+eg)) — single rcp
                float D1 = 1.0f + ef;
                float D2 = (1.0f + ei) * (1.0f + eg);
                float rD = __builtin_amdgcn_rcpf(D1 * D2);
                c[r] = (fmaf(c[r], D2, (1.0f - eg) * D1)) * rD;
                // h = o*tanh(c) = (1-ec)/((1+eo)(1+ec))
                float ec = __builtin_amdgcn_exp2f(c[r] * NEG2LOG2E);
                float ro = __builtin_amdgcn_rcpf((1.0f + eo) * (1.0f + ec));
                hv[r] = (1.0f - ec) * ro;
                hh[r] = bf16_rtn(hv[r]);
            }
            if (layer == 0) {
                *(s4v*)&h0b[wb][nl][ug + 4 * q] = hh;
            } else {
                *(s4v*)&h1b[wb][nl][ug + 4 * q] = hh;
                if (i == T) {   // h1(T-1), fp32, for the output head
                    float4 hw; hw.x = hv[0]; hw.y = hv[1]; hw.z = hv[2]; hw.w = hv[3];
                    *(float4*)&h1f[nl][ug + 4 * q] = hw;
                }
            }
        }
        __syncthreads();   // buffer wb becomes rb of the next step
    };

    #pragma unroll 1
    for (int i = 0; i < T; i += 2) {   // pairs (even: rb=0, odd: rb=1)
        body(i,     0, 1);
        body(i + 1, 1, 0);
    }
    body(T, 0, 1);                     // i = 512 (flush L2 step 511)

    // ---- output head: out[b0+n] = b_out + W_out . h1(T-1) ----
    if (tid < BT) {
        float acc = b_out[0];
        #pragma unroll
        for (int u = 0; u < H; ++u) acc = fmaf(W_out[u], h1f[tid][u], acc);
        out[b0 + tid] = acc;
    }
}

extern "C" void kernel_launch(void* const* d_in, const int* in_sizes, int n_in,
                              void* d_out, int out_size, void* d_ws, size_t ws_size,
                              hipStream_t stream) {
    const float* x     = (const float*)d_in[0];
    const float* W_ih0 = (const float*)d_in[1];
    const float* W_hh0 = (const float*)d_in[2];
    const float* b_ih0 = (const float*)d_in[3];
    const float* b_hh0 = (const float*)d_in[4];
    const float* W_ih1 = (const float*)d_in[5];
    const float* W_hh1 = (const float*)d_in[6];
    const float* b_ih1 = (const float*)d_in[7];
    const float* b_hh1 = (const float*)d_in[8];
    const float* W_out = (const float*)d_in[9];
    const float* b_out = (const float*)d_in[10];
    float* out = (float*)d_out;

    const int B = out_size;          // 4096
    lstm_bf16s<<<B / BT, BLK, 0, stream>>>(x, W_ih0, W_hh0, b_ih0, b_hh0,
                                           W_ih1, W_hh1, b_ih1, b_hh1,
                                           W_out, b_out, out);
}

// Round 16
// 286.452 us; speedup vs baseline: 1.2747x; 1.0316x over previous
//
#include <hip/hip_runtime.h>
#include <cmath>

// x [B=4096][T=512][D=4], H=32, gates 4H=128 (PyTorch order i,f,g,o).
constexpr int T   = 512;
constexpr int D   = 4;
constexpr int H   = 32;
constexpr int BT  = 16;    // batch cols per block — ALL real
constexpr int BLK = 256;   // 4 waves: (layer, unit-half)

constexpr float LOG2E     = 1.44269504088896340736f;
constexpr float NEG2LOG2E = -2.88539008177792681472f;

// x staged as FULL zero-padded B-fragments (8 shorts/t). Col stride 4104
// shorts = 2052 dwords ≡ 4 (mod 32): the 16 per-iter broadcast b128 reads
// land 2-way per bank-quad (free). 16*4104*2B = 131.3 KB.
constexpr int XSTRIDE = 4104;
// h row stride 40 shorts = 20 dwords: b128 frag reads have bank-quad index
// (5*nl+q) mod 8 — 5nl is a full residue cycle over nl(mod 8) -> exactly
// 2-way (nl vs nl+8) = free. (R15's 56 gave (7nl+q): 8-way, 5.2e6 conflicts.)
constexpr int HSTR = 40;

typedef short bf8 __attribute__((ext_vector_type(8)));  // 8 bf16 (4 VGPRs)
typedef short s4v __attribute__((ext_vector_type(4)));  // 4 bf16 (8B)
typedef float f4  __attribute__((ext_vector_type(4)));  // MFMA C/D

// fp32 -> bf16 round-to-nearest-even
static __device__ __forceinline__ short bf16_rtn(float v) {
    unsigned u = __float_as_uint(v);
    u += 0x7FFFu + ((u >> 16) & 1u);
    return (short)(u >> 16);
}

// R15 topology (wave = (layer, unit-half) owns all 4 gate tiles; lane-local
// i,f,g,o in C/D regs; single-product bf16 MFMAs, exp2-folded weights;
// plain-bf16 h; 1 barrier/iter) with the last identified overheads removed:
// - x pre-staged as padded fragments: L1 B-frag = ONE ds_read_b128
//   (A-operand zeros at k>=4 make the q>=1 fragment garbage harmless)
// - h stride 40: conflict-free fragment reads
// - t = i & 511 (no clamp); ds reads issued at the top of the body
__global__ __launch_bounds__(BLK, 1) void lstm_bf16p(
    const float* __restrict__ x,
    const float* __restrict__ W_ih0, const float* __restrict__ W_hh0,
    const float* __restrict__ b_ih0, const float* __restrict__ b_hh0,
    const float* __restrict__ W_ih1, const float* __restrict__ W_hh1,
    const float* __restrict__ b_ih1, const float* __restrict__ b_hh1,
    const float* __restrict__ W_out, const float* __restrict__ b_out,
    float* __restrict__ out)
{
    __shared__ __align__(16) short xbf[16 * XSTRIDE];   // 131.3 KB staged x frags
    __shared__ __align__(16) short h0b[2][16][HSTR];    // h, [buf][col][unit]
    __shared__ __align__(16) short h1b[2][16][HSTR];
    __shared__ __align__(16) float h1f[16][36];         // final h1 fp32 for the head

    const int tid   = threadIdx.x;
    const int w     = tid >> 6;
    const int lane  = tid & 63;
    const int q     = lane >> 4;       // quad
    const int nl    = lane & 15;       // batch col (all real)
    const int layer = w >> 1;          // 0: L1, 1: L2
    const int ug    = (w & 1) << 4;    // unit group offset 0 / 16
    const int b0    = blockIdx.x * BT;

    // ---- stage x -> zero-padded bf16 fragments ----
    // col-minor indexing: conflict-free LDS writes (banks 4*col mod 32 + t),
    // global reads still 64B-coalesced per col (4 consecutive t per wave).
    for (int idx = tid; idx < 16 * T; idx += BLK) {
        const int col = idx & 15;
        const int t   = idx >> 4;
        float4 xv = *(const float4*)(x + ((size_t)(b0 + col) * T + t) * D);
        bf8 v = {0, 0, 0, 0, 0, 0, 0, 0};
        v[0] = bf16_rtn(xv.x); v[1] = bf16_rtn(xv.y);
        v[2] = bf16_rtn(xv.z); v[3] = bf16_rtn(xv.w);
        *(bf8*)&xbf[col * XSTRIDE + t * 8] = v;
    }
    // zero both h buffers
    for (int idx = tid; idx < 2 * 16 * HSTR; idx += BLK) {
        (&h0b[0][0][0])[idx] = 0;
        (&h1b[0][0][0])[idx] = 0;
    }

    // ---- weights: tile g = gate type. A-frag row = 32g + ug + nl, k = 8q+j.
    // W1 dotted with h0 (L1: W_hh0, L2: W_ih1); W2 with the 2nd operand
    // (L1: W_ih0 vs x, K-padded; L2: W_hh1 vs h1). Rows pre-scaled for exp2.
    const float* W1 = layer ? W_ih1 : W_hh0;
    bf8 w1[4], w2[4];
    f4  bias[4];
    #pragma unroll
    for (int g = 0; g < 4; ++g) {
        const float sc = (g == 2) ? NEG2LOG2E : -LOG2E;
        const int row = 32 * g + ug + nl;
        #pragma unroll
        for (int j = 0; j < 8; ++j) {
            w1[g][j] = bf16_rtn(W1[row * H + 8 * q + j] * sc);
            float v2 = layer ? W_hh1[row * H + 8 * q + j]
                             : ((q == 0 && j < 4) ? W_ih0[row * D + j] : 0.0f);
            w2[g][j] = bf16_rtn(v2 * sc);
        }
        #pragma unroll
        for (int r = 0; r < 4; ++r) {
            const int gr = 32 * g + ug + 4 * q + r;
            bias[g][r] = sc * (layer ? (b_ih1[gr] + b_hh1[gr])
                                     : (b_ih0[gr] + b_hh0[gr]));
        }
    }

    float c[4] = {0.0f, 0.0f, 0.0f, 0.0f};   // cell state, fp32, lane-local

    const short* xcol = &xbf[nl * XSTRIDE];

    __syncthreads();

    // ---- one timestep; rb/wb are compile-time literals at each call site ----
    auto body = [&](const int i, const int rb, const int wb) {
        // issue all DS reads first
        bf8 b2;
        if (layer == 0) {   // x(i) fragment, pre-padded (i=T reads t=0, unused)
            b2 = *(const bf8*)&xcol[(i & (T - 1)) * 8];
        } else {            // h1(i-2)
            b2 = *(const bf8*)&h1b[rb][nl][8 * q];
        }
        bf8 b1 = *(const bf8*)&h0b[rb][nl][8 * q];              // h0(i-1)

        // ---- 8 MFMAs: 4 gate tiles x 2-chain (C starts at scaled bias) ----
        f4 acc[4];
        #pragma unroll
        for (int g = 0; g < 4; ++g) {
            f4 A = __builtin_amdgcn_mfma_f32_16x16x32_bf16(w2[g], b2, bias[g], 0, 0, 0);
            A    = __builtin_amdgcn_mfma_f32_16x16x32_bf16(w1[g], b1, A,       0, 0, 0);
            acc[g] = A;
        }

        // ---- lane-local state update: units ug+4q+r, col nl ----
        // acc = -log2e*z (i,f,o) / -2log2e*z (g): native exp2 domain.
        const bool act = layer ? (i >= 1) : (i < T);
        if (act) {
            s4v hh;
            float hv[4];
            #pragma unroll
            for (int r = 0; r < 4; ++r) {
                float ei = __builtin_amdgcn_exp2f(acc[0][r]);
                float ef = __builtin_amdgcn_exp2f(acc[1][r]);
                float eg = __builtin_amdgcn_exp2f(acc[2][r]);
                float eo = __builtin_amdgcn_exp2f(acc[3][r]);
                // c' = c/(1+ef) + (1-eg)/((1+ei)(1+eg)) — single rcp
                float D1 = 1.0f + ef;
                float D2 = (1.0f + ei) * (1.0f + eg);
                float rD = __builtin_amdgcn_rcpf(D1 * D2);
                c[r] = (fmaf(c[r], D2, (1.0f - eg) * D1)) * rD;
                // h = o*tanh(c) = (1-ec)/((1+eo)(1+ec))
                float ec = __builtin_amdgcn_exp2f(c[r] * NEG2LOG2E);
                float ro = __builtin_amdgcn_rcpf((1.0f + eo) * (1.0f + ec));
                hv[r] = (1.0f - ec) * ro;
                hh[r] = bf16_rtn(hv[r]);
            }
            if (layer == 0) {
                *(s4v*)&h0b[wb][nl][ug + 4 * q] = hh;
            } else {
                *(s4v*)&h1b[wb][nl][ug + 4 * q] = hh;
                if (i == T) {   // h1(T-1), fp32, for the output head
                    float4 hw; hw.x = hv[0]; hw.y = hv[1]; hw.z = hv[2]; hw.w = hv[3];
                    *(float4*)&h1f[nl][ug + 4 * q] = hw;
                }
            }
        }
        __syncthreads();   // buffer wb becomes rb of the next step
    };

    #pragma unroll 1
    for (int i = 0; i < T; i += 2) {   // pairs (even: rb=0, odd: rb=1)
        body(i,     0, 1);
        body(i + 1, 1, 0);
    }
    body(T, 0, 1);                     // i = 512 (flush L2 step 511)

    // ---- output head: out[b0+n] = b_out + W_out . h1(T-1) ----
    if (tid < BT) {
        float acc = b_out[0];
        #pragma unroll
        for (int u = 0; u < H; ++u) acc = fmaf(W_out[u], h1f[tid][u], acc);
        out[b0 + tid] = acc;
    }
}

extern "C" void kernel_launch(void* const* d_in, const int* in_sizes, int n_in,
                              void* d_out, int out_size, void* d_ws, size_t ws_size,
                              hipStream_t stream) {
    const float* x     = (const float*)d_in[0];
    const float* W_ih0 = (const float*)d_in[1];
    const float* W_hh0 = (const float*)d_in[2];
    const float* b_ih0 = (const float*)d_in[3];
    const float* b_hh0 = (const float*)d_in[4];
    const float* W_ih1 = (const float*)d_in[5];
    const float* W_hh1 = (const float*)d_in[6];
    const float* b_ih1 = (const float*)d_in[7];
    const float* b_hh1 = (const float*)d_in[8];
    const float* W_out = (const float*)d_in[9];
    const float* b_out = (const float*)d_in[10];
    float* out = (float*)d_out;

    const int B = out_size;          // 4096
    lstm_bf16p<<<B / BT, BLK, 0, stream>>>(x, W_ih0, W_hh0, b_ih0, b_hh0,
                                           W_ih1, W_hh1, b_ih1, b_hh1,
                                           W_out, b_out, out);
}